// Round 26
// baseline (109.427 us; speedup 1.0000x reference)
//
#include <hip/hip_runtime.h>

#define D 64
#define IN 128
#define NEG_SLOPE 0.01f

#define NSLICE 32          // level-1 slices
#define SUBPS  32          // sub-buckets per slice
#define NSUB   1024        // NSLICE*SUBPS
#define EPB_A  2048        // edges per partA block (8*256), int4-vectorized
#define HALF   49          // nodes per half-sub-bucket (ceil(98/2))
#define CAP2   1152        // max edges per half-bucket staged in LDS (mean 781 + 13 sigma)
#define CAP_S  53248       // static per-slice region (mean 50000 + ~14 sigma)
#define CAP_SUB 2304       // static per-sub-bucket region (mean 1562 + ~18 sigma)

using f32x4  = __attribute__((ext_vector_type(4))) float;
using bf16x8 = __attribute__((ext_vector_type(8))) short;
using u16x8  = __attribute__((ext_vector_type(8))) unsigned short;

__device__ __forceinline__ short f2bf(float f) {
    unsigned u = __float_as_uint(f);
    u = u + 0x7FFFu + ((u >> 16) & 1u);   // RNE to bf16
    return (short)(u >> 16);
}
__device__ __forceinline__ float bf2f(unsigned short u) {
    return __uint_as_float((unsigned)u << 16);
}
// exact n/divisor via magic mult (M = ceil(2^32/divisor))
__device__ __forceinline__ int mdiv(int n, unsigned M) {
    return (int)__umulhi((unsigned)n, M);
}

// ---------------- Kernel 1: level-1 partition (standalone, low VGPR) ---------
__global__ __launch_bounds__(256) void k_partA(
    const int* __restrict__ src, const int* __restrict__ dst,
    int* __restrict__ slice_cur, int* __restrict__ partA,
    int n_edges, int nps1, unsigned M1)
{
    __shared__ int loff[NSLICE + 1], lbase[NSLICE], lcur[NSLICE];
    __shared__ int lsort[EPB_A];
    const int tid = threadIdx.x;
    const int e0 = blockIdx.x * EPB_A;
    const int e1 = min(e0 + EPB_A, n_edges);

    if (tid < NSLICE) { loff[tid] = 0; lcur[tid] = 0; }
    __syncthreads();

    const int4* dst4 = (const int4*)dst;
    const int4* src4 = (const int4*)src;
    int myp[8], mysl[8];
    #pragma unroll
    for (int c = 0; c < 2; ++c) {
        int b4 = (e0 >> 2) + c * 256 + tid;       // int4 index
        bool v4 = (b4 * 4 < e1);                  // n_edges % 4 == 0 for this input
        int4 d4 = v4 ? dst4[b4] : make_int4(0, 0, 0, 0);
        int4 s4 = v4 ? src4[b4] : make_int4(0, 0, 0, 0);
        const int* dp = (const int*)&d4;
        const int* sp = (const int*)&s4;
        #pragma unroll
        for (int k = 0; k < 4; ++k) {
            int j = c * 4 + k;
            mysl[j] = -1;
            int idx = b4 * 4 + k;
            if (v4 && idx < e1) {
                int d = dp[k], s = sp[k];
                int sl = mdiv(d, M1);
                mysl[j] = sl;
                myp[j]  = s | ((d - sl * nps1) << 17);
                atomicAdd(&loff[sl], 1);
            }
        }
    }
    __syncthreads();
    // 32-lane shfl exclusive scan of loff
    if (tid < NSLICE) {
        int v = loff[tid];
        int sc = v;
        #pragma unroll
        for (int o = 1; o < NSLICE; o <<= 1) {
            int t2 = __shfl_up(sc, o, 64);
            if (tid >= o) sc += t2;
        }
        loff[tid] = sc - v;
        if (tid == NSLICE - 1) loff[NSLICE] = sc;
    }
    __syncthreads();
    if (tid < NSLICE)
        lbase[tid] = tid * CAP_S + atomicAdd(&slice_cur[tid * 16], loff[tid + 1] - loff[tid]);
    #pragma unroll
    for (int j = 0; j < 8; ++j)
        if (mysl[j] >= 0) {
            int r = atomicAdd(&lcur[mysl[j]], 1);
            lsort[loff[mysl[j]] + r] = myp[j];
        }
    __syncthreads();
    for (int s = 0; s < NSLICE; ++s) {
        int b = loff[s], e = loff[s + 1], gb = lbase[s];
        int lim = (s + 1) * CAP_S;          // overflow guard (never hit)
        for (int i = b + tid; i < e; i += 256) {
            int pos = gb + (i - b);
            if (pos < lim) partA[pos] = lsort[i];
        }
    }
}

// ---------------- Kernel 2: dual-role: level-2 partition ∥ z-projection ------
// blocks [0, NSUB): partB role; blocks [NSUB, +n_proj): projection role
__global__ __launch_bounds__(256) void k_partB_proj(
    const int* __restrict__ partA, const int* __restrict__ slice_cur,
    int* __restrict__ sub_cur, int* __restrict__ part2, int nps2, unsigned M2,
    const float* __restrict__ h, const float* __restrict__ fc_w,
    const float* __restrict__ attn_w,
    unsigned short* __restrict__ zb, float* __restrict__ a_src, float* __restrict__ a_dst,
    int n_nodes)
{
    __shared__ int smem[4352];    // union: partB {loff,lbase,lcur,lsort} / proj zst

    if (blockIdx.x < NSUB) {
        // ================= partB role =================
        int* loff  = smem;            // [SUBPS+1]
        int* lbase = smem + 40;       // [SUBPS]
        int* lcur  = smem + 80;       // [SUBPS]
        int* lsort = smem + 128;      // [2048]
        const int tid   = threadIdx.x;
        const int slice = blockIdx.x >> 5;
        const int bid   = blockIdx.x & 31;
        const int s0   = slice * CAP_S;
        const int cntS = min(slice_cur[slice * 16], CAP_S);
        const int chunk = (cntS + 31) >> 5;
        int c0 = s0 + bid * chunk;
        int c1 = min(c0 + chunk, s0 + cntS);

        for (int r0 = c0; r0 < c1; r0 += 2048) {
            int r1 = min(r0 + 2048, c1);
            if (tid < SUBPS) { loff[tid] = 0; lcur[tid] = 0; }
            __syncthreads();
            int myp[8], mysb[8];
            #pragma unroll
            for (int j = 0; j < 8; ++j) {
                int i = r0 + j * 256 + tid;
                mysb[j] = -1;
                if (i < r1) {
                    int p = partA[i];
                    int dloc = p >> 17;
                    int sb = mdiv(dloc, M2);
                    mysb[j] = sb;
                    myp[j]  = (p & 0x1FFFF) | ((dloc - sb * nps2) << 17);
                    atomicAdd(&loff[sb], 1);
                }
            }
            __syncthreads();
            if (tid < SUBPS) {
                int v = loff[tid];
                int sc = v;
                #pragma unroll
                for (int o = 1; o < SUBPS; o <<= 1) {
                    int t2 = __shfl_up(sc, o, 64);
                    if (tid >= o) sc += t2;
                }
                loff[tid] = sc - v;
                if (tid == SUBPS - 1) loff[SUBPS] = sc;
            }
            __syncthreads();
            if (tid < SUBPS) {
                int sub = slice * SUBPS + tid;
                lbase[tid] = sub * CAP_SUB + atomicAdd(&sub_cur[sub], loff[tid + 1] - loff[tid]);
            }
            #pragma unroll
            for (int j = 0; j < 8; ++j)
                if (mysb[j] >= 0) {
                    int r = atomicAdd(&lcur[mysb[j]], 1);
                    lsort[loff[mysb[j]] + r] = myp[j];
                }
            __syncthreads();
            for (int s = 0; s < SUBPS; ++s) {
                int b = loff[s], e = loff[s + 1], gb = lbase[s];
                int lim = (slice * SUBPS + s + 1) * CAP_SUB;   // overflow guard
                for (int i = b + tid; i < e; i += 256) {
                    int pos = gb + (i - b);
                    if (pos < lim) part2[pos] = lsort[i];
                }
            }
            __syncthreads();
        }
        return;
    }

    // ================= projection role (256 nodes/block) =====================
    float* zst = (float*)smem;    // [4][16][68] -> wid*1088 + row*68 + col
    const int wid  = threadIdx.x >> 6;
    const int lane = threadIdx.x & 63;
    const int g16  = lane >> 4;
    const int l16  = lane & 15;

    bf16x8 bfrag[4][4];
    #pragma unroll
    for (int t = 0; t < 4; ++t) {
        const float* wrow = fc_w + (size_t)(t * 16 + l16) * IN + g16 * 8;
        #pragma unroll
        for (int ks = 0; ks < 4; ++ks) {
            f32x4 w0 = *(const f32x4*)(wrow + ks * 32);
            f32x4 w1 = *(const f32x4*)(wrow + ks * 32 + 4);
            bf16x8 b;
            b[0] = f2bf(w0[0]); b[1] = f2bf(w0[1]); b[2] = f2bf(w0[2]); b[3] = f2bf(w0[3]);
            b[4] = f2bf(w1[0]); b[5] = f2bf(w1[1]); b[6] = f2bf(w1[2]); b[7] = f2bf(w1[3]);
            bfrag[t][ks] = b;
        }
    }

    float awx[4], awy[4];
    #pragma unroll
    for (int t = 0; t < 4; ++t) {
        awx[t] = attn_w[t * 16 + l16];
        awy[t] = attn_w[D + t * 16 + l16];
    }

    const int grp0 = (blockIdx.x - NSUB) * 16 + wid * 4;
    #pragma unroll
    for (int it = 0; it < 4; ++it) {
        const int gb = (grp0 + it) * 16;
        if (gb >= n_nodes) break;

        const float* hrow = h + (size_t)(gb + l16) * IN + g16 * 8;
        bf16x8 afrag[4];
        #pragma unroll
        for (int ks = 0; ks < 4; ++ks) {
            f32x4 h0 = *(const f32x4*)(hrow + ks * 32);
            f32x4 h1 = *(const f32x4*)(hrow + ks * 32 + 4);
            bf16x8 a;
            a[0] = f2bf(h0[0]); a[1] = f2bf(h0[1]); a[2] = f2bf(h0[2]); a[3] = f2bf(h0[3]);
            a[4] = f2bf(h1[0]); a[5] = f2bf(h1[1]); a[6] = f2bf(h1[2]); a[7] = f2bf(h1[3]);
            afrag[ks] = a;
        }

        f32x4 acc[4] = {f32x4{0,0,0,0}, f32x4{0,0,0,0}, f32x4{0,0,0,0}, f32x4{0,0,0,0}};
        #pragma unroll
        for (int t = 0; t < 4; ++t)
            #pragma unroll
            for (int ks = 0; ks < 4; ++ks)
                acc[t] = __builtin_amdgcn_mfma_f32_16x16x32_bf16(
                    afrag[ks], bfrag[t][ks], acc[t], 0, 0, 0);

        #pragma unroll
        for (int t = 0; t < 4; ++t)
            #pragma unroll
            for (int r = 0; r < 4; ++r)
                zst[wid * 1088 + (g16 * 4 + r) * 68 + t * 16 + l16] = acc[t][r];

        const int rrow = lane >> 2;
        const int rcol = (lane & 3) * 16;
        const float* zr0 = &zst[wid * 1088 + rrow * 68 + rcol];
        f32x4 v0 = *(const f32x4*)(zr0);
        f32x4 v1 = *(const f32x4*)(zr0 + 4);
        f32x4 v2 = *(const f32x4*)(zr0 + 8);
        f32x4 v3 = *(const f32x4*)(zr0 + 12);
        u16x8 p0, p1;
        p0[0] = (unsigned short)f2bf(v0[0]); p0[1] = (unsigned short)f2bf(v0[1]);
        p0[2] = (unsigned short)f2bf(v0[2]); p0[3] = (unsigned short)f2bf(v0[3]);
        p0[4] = (unsigned short)f2bf(v1[0]); p0[5] = (unsigned short)f2bf(v1[1]);
        p0[6] = (unsigned short)f2bf(v1[2]); p0[7] = (unsigned short)f2bf(v1[3]);
        p1[0] = (unsigned short)f2bf(v2[0]); p1[1] = (unsigned short)f2bf(v2[1]);
        p1[2] = (unsigned short)f2bf(v2[2]); p1[3] = (unsigned short)f2bf(v2[3]);
        p1[4] = (unsigned short)f2bf(v3[0]); p1[5] = (unsigned short)f2bf(v3[1]);
        p1[6] = (unsigned short)f2bf(v3[2]); p1[7] = (unsigned short)f2bf(v3[3]);
        *(u16x8*)&zb[(size_t)(gb + rrow) * D + rcol]     = p0;
        *(u16x8*)&zb[(size_t)(gb + rrow) * D + rcol + 8] = p1;

        #pragma unroll
        for (int r = 0; r < 4; ++r) {
            float as = acc[0][r] * awx[0] + acc[1][r] * awx[1]
                     + acc[2][r] * awx[2] + acc[3][r] * awx[3];
            float ad = acc[0][r] * awy[0] + acc[1][r] * awy[1]
                     + acc[2][r] * awy[2] + acc[3][r] * awy[3];
            #pragma unroll
            for (int o = 1; o < 16; o <<= 1) {
                as += __shfl_xor(as, o, 64);
                ad += __shfl_xor(ad, o, 64);
            }
            if (l16 == 0) {
                a_src[gb + g16 * 4 + r] = as;
                a_dst[gb + g16 * 4 + r] = ad;
            }
        }
    }
}

// ---------------- Kernel 3: fused exp-at-stage + gather ----------------------
__global__ __launch_bounds__(256) void k_fused(
    const int* __restrict__ part2, const int* __restrict__ sub_cur,
    const float* __restrict__ a_src, const float* __restrict__ a_dst,
    const u16x8* __restrict__ zb8, float4* __restrict__ out4,
    int n_nodes, int nps2)
{
    __shared__ int   sdeg[56], scur[56];
    __shared__ float sden[56];
    __shared__ int   soff[65];        // full-wave scan writes soff[1..64]
    __shared__ int   sstage[CAP_SUB]; // whole sub-bucket staged once
    __shared__ int2  sedge[CAP2];     // {src<<3, exp(e) bits}

    const int tid  = threadIdx.x;
    const int sub  = blockIdx.x >> 1;
    const int half = blockIdx.x & 1;
    const int nb0  = sub * nps2;
    if (nb0 >= n_nodes) return;
    const int nn   = min(nps2, n_nodes - nb0);
    const int lo   = half * HALF;
    const int hi   = min(nn, lo + HALF);
    const int nloc = hi - lo;
    if (nloc <= 0) return;
    const int s0  = sub * CAP_SUB;
    const int cnt = min(sub_cur[sub], CAP_SUB);

    for (int i = tid; i < 56; i += 256) { sdeg[i] = 0; scur[i] = 0; sden[i] = 0.f; }
    __syncthreads();

    for (int i = tid; i < cnt; i += 256) {
        int p = part2[s0 + i];
        sstage[i] = p;
        int local = p >> 17;
        if (local >= lo && local < hi) atomicAdd(&sdeg[local - lo], 1);
    }
    __syncthreads();

    if (tid < 64) {
        int v = (tid < nloc) ? sdeg[tid] : 0;
        int sc = v;
        #pragma unroll
        for (int o = 1; o < 64; o <<= 1) {
            int t2 = __shfl_up(sc, o, 64);
            if (tid >= o) sc += t2;
        }
        soff[tid + 1] = sc;
        if (tid == 0) soff[0] = 0;
    }
    __syncthreads();

    const bool fits = (soff[nloc] <= CAP2);

    if (fits) {
        for (int i = tid; i < cnt; i += 256) {
            int p = sstage[i];
            int local = p >> 17;
            if (local >= lo && local < hi) {
                int l2 = local - lo;
                int s = p & 0x1FFFF;
                int pos = soff[l2] + atomicAdd(&scur[l2], 1);
                float e = a_src[s] + a_dst[nb0 + local];
                e = (e >= 0.f) ? e : NEG_SLOPE * e;
                float ex = __expf(e);
                sedge[pos] = make_int2(s << 3, __float_as_int(ex));
                atomicAdd(&sden[l2], ex);
            }
        }
    }
    __syncthreads();

    if (fits) {
        const int group = tid >> 3;
        const int l8    = tid & 7;
        for (int n = group; n < nloc; n += 32) {
            int beg = soff[n], deg = sdeg[n];
            f32x4 a0 = {0.f,0.f,0.f,0.f}, a1 = {0.f,0.f,0.f,0.f};
            for (int i = 0; i < deg; ++i) {
                int2 me = sedge[beg + i];
                float w = __int_as_float(me.y);
                u16x8 zr = zb8[(size_t)me.x + l8];
                a0[0] = fmaf(w, bf2f(zr[0]), a0[0]);
                a0[1] = fmaf(w, bf2f(zr[1]), a0[1]);
                a0[2] = fmaf(w, bf2f(zr[2]), a0[2]);
                a0[3] = fmaf(w, bf2f(zr[3]), a0[3]);
                a1[0] = fmaf(w, bf2f(zr[4]), a1[0]);
                a1[1] = fmaf(w, bf2f(zr[5]), a1[1]);
                a1[2] = fmaf(w, bf2f(zr[6]), a1[2]);
                a1[3] = fmaf(w, bf2f(zr[7]), a1[3]);
            }
            float inv = (deg > 0) ? 1.f / sden[n] : 0.f;
            out4[(size_t)(nb0 + lo + n) * 16 + l8 * 2] =
                make_float4(a0[0] * inv, a0[1] * inv, a0[2] * inv, a0[3] * inv);
            out4[(size_t)(nb0 + lo + n) * 16 + l8 * 2 + 1] =
                make_float4(a1[0] * inv, a1[1] * inv, a1[2] * inv, a1[3] * inv);
        }
    } else {
        const ushort4* zb4 = (const ushort4*)zb8;
        const int wave = tid >> 6, lane = tid & 63, l16 = lane & 15;
        for (int n = wave; n < nloc; n += 4) {
            int deg = 0;
            float adn = a_dst[nb0 + lo + n];
            float dsum = 0.f;
            float4 acc = make_float4(0.f, 0.f, 0.f, 0.f);
            for (int c = 0; c < cnt; c += 64) {
                int j = c + lane;
                float ex = 0.f;
                if (j < cnt) {
                    int p = sstage[j];
                    if ((p >> 17) == lo + n) {
                        float e = a_src[p & 0x1FFFF] + adn;
                        e = (e >= 0.f) ? e : NEG_SLOPE * e;
                        ex = __expf(e);
                        ++deg;
                    }
                }
                float exs = ex;
                #pragma unroll
                for (int o = 32; o > 0; o >>= 1) exs += __shfl_xor(exs, o, 64);
                dsum += exs;
            }
            #pragma unroll
            for (int o = 32; o > 0; o >>= 1) deg += __shfl_xor(deg, o, 64);
            for (int j = 0; j < cnt; ++j) {
                int p = sstage[j];
                if ((p >> 17) == lo + n) {
                    int s = p & 0x1FFFF;
                    float e = a_src[s] + adn;
                    e = (e >= 0.f) ? e : NEG_SLOPE * e;
                    float w = __expf(e);
                    if (lane < 16) {
                        ushort4 zr = zb4[(size_t)(s << 4) + l16];
                        acc.x = fmaf(w, bf2f(zr.x), acc.x);
                        acc.y = fmaf(w, bf2f(zr.y), acc.y);
                        acc.z = fmaf(w, bf2f(zr.z), acc.z);
                        acc.w = fmaf(w, bf2f(zr.w), acc.w);
                    }
                }
            }
            #pragma unroll
            for (int o = 16; o <= 32; o <<= 1) {
                acc.x += __shfl_xor(acc.x, o, 64);
                acc.y += __shfl_xor(acc.y, o, 64);
                acc.z += __shfl_xor(acc.z, o, 64);
                acc.w += __shfl_xor(acc.w, o, 64);
            }
            if (lane < 16) {
                float inv = (deg > 0) ? 1.f / dsum : 0.f;
                out4[(size_t)(nb0 + lo + n) * 16 + l16] =
                    make_float4(acc.x * inv, acc.y * inv, acc.z * inv, acc.w * inv);
            }
        }
    }
}

extern "C" void kernel_launch(void* const* d_in, const int* in_sizes, int n_in,
                              void* d_out, int out_size, void* d_ws, size_t ws_size,
                              hipStream_t stream) {
    const float* h      = (const float*)d_in[0];
    const int*   src    = (const int*)d_in[1];
    const int*   dst    = (const int*)d_in[2];
    const float* fc_w   = (const float*)d_in[3];
    const float* attn_w = (const float*)d_in[4];

    const int n_nodes = in_sizes[0] / IN;
    const int n_edges = in_sizes[1];
    float* out = (float*)d_out;

    const int nps2 = (n_nodes + NSUB - 1) / NSUB;   // nodes per sub-bucket (98)
    const int nps1 = nps2 * SUBPS;                  // nodes per slice (3136)
    const int nba  = (n_edges + EPB_A - 1) / EPB_A; // partA blocks (782)
    const int n_proj = (n_nodes + 255) / 256;       // projection blocks (391)
    const unsigned M1 = (unsigned)((0x100000000ULL + nps1 - 1) / (unsigned)nps1);
    const unsigned M2 = (unsigned)((0x100000000ULL + nps2 - 1) / (unsigned)nps2);

    // workspace layout
    char* p = (char*)d_ws;
    unsigned short* zb = (unsigned short*)p; p += (size_t)n_nodes * D * sizeof(unsigned short);
    int*   partA     = (int*)p;   p += (size_t)NSLICE * CAP_S * sizeof(int);
    int*   part2     = (int*)p;   p += (size_t)NSUB * CAP_SUB * sizeof(int);
    float* a_src     = (float*)p; p += (size_t)n_nodes * sizeof(float);
    float* a_dst     = (float*)p; p += (size_t)n_nodes * sizeof(float);
    int*   slice_cur = (int*)p;   p += NSLICE * 16 * sizeof(int);
    int*   sub_cur   = (int*)p;   p += NSUB * sizeof(int);

    // zero both cursor arrays (contiguous) each call
    hipMemsetAsync(slice_cur, 0, (NSLICE * 16 + NSUB) * sizeof(int), stream);

    k_partA<<<dim3(nba), dim3(256), 0, stream>>>(
        src, dst, slice_cur, partA, n_edges, nps1, M1);
    k_partB_proj<<<dim3(NSUB + n_proj), dim3(256), 0, stream>>>(
        partA, slice_cur, sub_cur, part2, nps2, M2,
        h, fc_w, attn_w, zb, a_src, a_dst, n_nodes);
    k_fused<<<dim3(NSUB * 2), dim3(256), 0, stream>>>(
        part2, sub_cur, a_src, a_dst, (const u16x8*)zb, (float4*)out, n_nodes, nps2);
}

// Round 27
// 84.840 us; speedup vs baseline: 1.2898x; 1.2898x over previous
//
#include <hip/hip_runtime.h>

#define D 64
#define IN 128
#define NEG_SLOPE 0.01f

#define NSLICE 32          // level-1 slices
#define SUBPS  32          // sub-buckets per slice
#define NSUB   1024        // NSLICE*SUBPS
#define EPB_A  3328        // edges per partA block (13*256)
#define EPT_A  13
#define HALF   49          // nodes per half-sub-bucket (ceil(98/2))
#define CAP2   1152        // max edges per half-bucket staged in LDS (mean 781 + 13 sigma)
#define CAP_S  53248       // static per-slice region (mean 50000 + ~14 sigma)
#define CAP_SUB 2304       // static per-sub-bucket region (mean 1562 + ~18 sigma)

using f32x4  = __attribute__((ext_vector_type(4))) float;
using bf16x8 = __attribute__((ext_vector_type(8))) short;
using u16x8  = __attribute__((ext_vector_type(8))) unsigned short;

__device__ __forceinline__ short f2bf(float f) {
    unsigned u = __float_as_uint(f);
    u = u + 0x7FFFu + ((u >> 16) & 1u);   // RNE to bf16
    return (short)(u >> 16);
}
__device__ __forceinline__ float bf2f(unsigned short u) {
    return __uint_as_float((unsigned)u << 16);
}
// exact n/divisor via magic mult (M = ceil(2^32/divisor))
__device__ __forceinline__ int mdiv(int n, unsigned M) {
    return (int)__umulhi((unsigned)n, M);
}

// z tiled layout: zb[node*64 + l16*4 + t] holds column (t*16 + l16).
// proj writes it coalesced straight from MFMA acc (no LDS round trip);
// k_fused's gather loads are unchanged, only the out-write mapping differs.

// ---------------- Kernel 1: dual-role: level-1 partition ∥ z-projection ------
// launch_bounds(256,8): force VGPR<=64 -> 8 waves/SIMD (proj was the 100-VGPR cap)
__global__ __launch_bounds__(256, 8) void k_partA_proj(
    const int* __restrict__ src, const int* __restrict__ dst,
    int* __restrict__ slice_cur, int* __restrict__ partA,
    int n_edges, int nps1, unsigned M1, int n_partA,
    const float* __restrict__ h, const float* __restrict__ fc_w,
    const float* __restrict__ attn_w,
    unsigned short* __restrict__ zb, float* __restrict__ a_src, float* __restrict__ a_dst,
    int n_nodes)
{
    __shared__ int smem[4096];    // union: partA {loff,lbase,lcur,lsort} / proj fc_w-bf16 table

    if (blockIdx.x < n_partA) {
        // ================= partA role =================
        int* loff  = smem;            // [NSLICE+1]
        int* lbase = smem + 40;       // [NSLICE]
        int* lcur  = smem + 80;       // [NSLICE]
        int* lsort = smem + 128;      // [EPB_A]
        const int tid = threadIdx.x;
        const int e0 = blockIdx.x * EPB_A;
        const int e1 = min(e0 + EPB_A, n_edges);

        if (tid < NSLICE) { loff[tid] = 0; lcur[tid] = 0; }
        __syncthreads();

        int myp[EPT_A], mysl[EPT_A];
        #pragma unroll
        for (int j = 0; j < EPT_A; ++j) {
            int i = e0 + j * 256 + tid;
            mysl[j] = -1;
            if (i < e1) {
                int d = dst[i], s = src[i];
                int sl = mdiv(d, M1);
                mysl[j] = sl;
                myp[j]  = s | ((d - sl * nps1) << 17);
                atomicAdd(&loff[sl], 1);
            }
        }
        __syncthreads();
        if (tid < NSLICE) {
            int v = loff[tid];
            int sc = v;
            #pragma unroll
            for (int o = 1; o < NSLICE; o <<= 1) {
                int t2 = __shfl_up(sc, o, 64);
                if (tid >= o) sc += t2;
            }
            loff[tid] = sc - v;
            if (tid == NSLICE - 1) loff[NSLICE] = sc;
        }
        __syncthreads();
        if (tid < NSLICE)
            lbase[tid] = tid * CAP_S + atomicAdd(&slice_cur[tid * 16], loff[tid + 1] - loff[tid]);
        #pragma unroll
        for (int j = 0; j < EPT_A; ++j)
            if (mysl[j] >= 0) {
                int r = atomicAdd(&lcur[mysl[j]], 1);
                lsort[loff[mysl[j]] + r] = myp[j];
            }
        __syncthreads();
        for (int s = 0; s < NSLICE; ++s) {
            int b = loff[s], e = loff[s + 1], gb = lbase[s];
            int lim = (s + 1) * CAP_S;          // overflow guard (never hit)
            for (int i = b + tid; i < e; i += 256) {
                int pos = gb + (i - b);
                if (pos < lim) partA[pos] = lsort[i];
            }
        }
        return;
    }

    // ================= projection role (256 nodes/block) =====================
    // fc_w staged in LDS as bf16 fragment table: [t][ks][g16][l16][8]
    unsigned short* wlds = (unsigned short*)smem;   // 16 KB
    const int tid  = threadIdx.x;
    const int wid  = tid >> 6;
    const int lane = tid & 63;
    const int g16  = lane >> 4;
    const int l16  = lane & 15;

    for (int c = tid; c < 1024; c += 256) {   // 1024 chunks of 8 f32
        int row = c >> 4;                     // 0..63
        int cb  = (c & 15) * 8;               // col base
        const float* wp = fc_w + (size_t)row * IN + cb;
        f32x4 w0 = *(const f32x4*)(wp);
        f32x4 w1 = *(const f32x4*)(wp + 4);
        int t   = row >> 4, lv = row & 15;
        int ks  = cb >> 5,  gv = (cb >> 3) & 3;
        u16x8 b;
        b[0] = (unsigned short)f2bf(w0[0]); b[1] = (unsigned short)f2bf(w0[1]);
        b[2] = (unsigned short)f2bf(w0[2]); b[3] = (unsigned short)f2bf(w0[3]);
        b[4] = (unsigned short)f2bf(w1[0]); b[5] = (unsigned short)f2bf(w1[1]);
        b[6] = (unsigned short)f2bf(w1[2]); b[7] = (unsigned short)f2bf(w1[3]);
        *(u16x8*)&wlds[(size_t)(((t * 4 + ks) * 4 + gv) * 16 + lv) * 8] = b;
    }
    __syncthreads();

    float awx[4], awy[4];
    #pragma unroll
    for (int t = 0; t < 4; ++t) {
        awx[t] = attn_w[t * 16 + l16];
        awy[t] = attn_w[D + t * 16 + l16];
    }

    const int grp0 = (blockIdx.x - n_partA) * 16 + wid * 4;
    #pragma unroll
    for (int it = 0; it < 4; ++it) {
        const int gb = (grp0 + it) * 16;
        if (gb >= n_nodes) break;

        const float* hrow = h + (size_t)(gb + l16) * IN + g16 * 8;
        bf16x8 afrag[4];
        #pragma unroll
        for (int ks = 0; ks < 4; ++ks) {
            f32x4 h0 = *(const f32x4*)(hrow + ks * 32);
            f32x4 h1 = *(const f32x4*)(hrow + ks * 32 + 4);
            bf16x8 a;
            a[0] = f2bf(h0[0]); a[1] = f2bf(h0[1]); a[2] = f2bf(h0[2]); a[3] = f2bf(h0[3]);
            a[4] = f2bf(h1[0]); a[5] = f2bf(h1[1]); a[6] = f2bf(h1[2]); a[7] = f2bf(h1[3]);
            afrag[ks] = a;
        }

        f32x4 acc[4] = {f32x4{0,0,0,0}, f32x4{0,0,0,0}, f32x4{0,0,0,0}, f32x4{0,0,0,0}};
        #pragma unroll
        for (int t = 0; t < 4; ++t)
            #pragma unroll
            for (int ks = 0; ks < 4; ++ks) {
                bf16x8 b = *(const bf16x8*)&wlds[(size_t)(((t * 4 + ks) * 4 + g16) * 16 + l16) * 8];
                acc[t] = __builtin_amdgcn_mfma_f32_16x16x32_bf16(afrag[ks], b, acc[t], 0, 0, 0);
            }

        // tiled z store: position l16*4+t holds col t*16+l16 (8B per row, coalesced)
        #pragma unroll
        for (int r = 0; r < 4; ++r) {
            ushort4 st;
            st.x = (unsigned short)f2bf(acc[0][r]);
            st.y = (unsigned short)f2bf(acc[1][r]);
            st.z = (unsigned short)f2bf(acc[2][r]);
            st.w = (unsigned short)f2bf(acc[3][r]);
            *(ushort4*)&zb[(size_t)(gb + g16 * 4 + r) * D + l16 * 4] = st;
        }

        #pragma unroll
        for (int r = 0; r < 4; ++r) {
            float as = acc[0][r] * awx[0] + acc[1][r] * awx[1]
                     + acc[2][r] * awx[2] + acc[3][r] * awx[3];
            float ad = acc[0][r] * awy[0] + acc[1][r] * awy[1]
                     + acc[2][r] * awy[2] + acc[3][r] * awy[3];
            #pragma unroll
            for (int o = 1; o < 16; o <<= 1) {
                as += __shfl_xor(as, o, 64);
                ad += __shfl_xor(ad, o, 64);
            }
            if (l16 == 0) {
                a_src[gb + g16 * 4 + r] = as;
                a_dst[gb + g16 * 4 + r] = ad;
            }
        }
    }
}

// ---------------- Kernel 2: level-2 partition within slice -------------------
__global__ __launch_bounds__(256) void k_partB(
    const int* __restrict__ partA, const int* __restrict__ slice_cur,
    int* __restrict__ sub_cur, int* __restrict__ part2, int nps2, unsigned M2)
{
    __shared__ int loff[SUBPS + 1], lbase[SUBPS], lcur[SUBPS];
    __shared__ int lsort[2048];
    const int tid   = threadIdx.x;
    const int slice = blockIdx.x >> 5;
    const int bid   = blockIdx.x & 31;
    const int s0   = slice * CAP_S;
    const int cntS = min(slice_cur[slice * 16], CAP_S);
    const int chunk = (cntS + 31) >> 5;
    int c0 = s0 + bid * chunk;
    int c1 = min(c0 + chunk, s0 + cntS);

    for (int r0 = c0; r0 < c1; r0 += 2048) {
        int r1 = min(r0 + 2048, c1);
        if (tid < SUBPS) { loff[tid] = 0; lcur[tid] = 0; }
        __syncthreads();
        int myp[8], mysb[8];
        #pragma unroll
        for (int j = 0; j < 8; ++j) {
            int i = r0 + j * 256 + tid;
            mysb[j] = -1;
            if (i < r1) {
                int p = partA[i];
                int dloc = p >> 17;
                int sb = mdiv(dloc, M2);
                mysb[j] = sb;
                myp[j]  = (p & 0x1FFFF) | ((dloc - sb * nps2) << 17);
                atomicAdd(&loff[sb], 1);
            }
        }
        __syncthreads();
        if (tid < SUBPS) {
            int v = loff[tid];
            int sc = v;
            #pragma unroll
            for (int o = 1; o < SUBPS; o <<= 1) {
                int t2 = __shfl_up(sc, o, 64);
                if (tid >= o) sc += t2;
            }
            loff[tid] = sc - v;
            if (tid == SUBPS - 1) loff[SUBPS] = sc;
        }
        __syncthreads();
        if (tid < SUBPS) {
            int sub = slice * SUBPS + tid;
            lbase[tid] = sub * CAP_SUB + atomicAdd(&sub_cur[sub], loff[tid + 1] - loff[tid]);
        }
        #pragma unroll
        for (int j = 0; j < 8; ++j)
            if (mysb[j] >= 0) {
                int r = atomicAdd(&lcur[mysb[j]], 1);
                lsort[loff[mysb[j]] + r] = myp[j];
            }
        __syncthreads();
        for (int s = 0; s < SUBPS; ++s) {
            int b = loff[s], e = loff[s + 1], gb = lbase[s];
            int lim = (slice * SUBPS + s + 1) * CAP_SUB;   // overflow guard
            for (int i = b + tid; i < e; i += 256) {
                int pos = gb + (i - b);
                if (pos < lim) part2[pos] = lsort[i];
            }
        }
        __syncthreads();
    }
}

// ---------------- Kernel 3: fused exp-at-stage + gather ----------------------
// gather loads unchanged (tiled zb rows are still 128B contiguous per node);
// out-write remapped for the tiled layout: lane l8 holds cols {t*16+2*l8(+1)}
__global__ __launch_bounds__(256) void k_fused(
    const int* __restrict__ part2, const int* __restrict__ sub_cur,
    const float* __restrict__ a_src, const float* __restrict__ a_dst,
    const u16x8* __restrict__ zb8, float* __restrict__ out,
    int n_nodes, int nps2)
{
    __shared__ int   sdeg[56], scur[56];
    __shared__ float sden[56];
    __shared__ int   soff[65];        // full-wave scan writes soff[1..64]
    __shared__ int   sstage[CAP_SUB]; // whole sub-bucket staged once
    __shared__ int2  sedge[CAP2];     // {src<<3, exp(e) bits}

    const int tid  = threadIdx.x;
    const int sub  = blockIdx.x >> 1;
    const int half = blockIdx.x & 1;
    const int nb0  = sub * nps2;
    if (nb0 >= n_nodes) return;
    const int nn   = min(nps2, n_nodes - nb0);
    const int lo   = half * HALF;
    const int hi   = min(nn, lo + HALF);
    const int nloc = hi - lo;
    if (nloc <= 0) return;
    const int s0  = sub * CAP_SUB;
    const int cnt = min(sub_cur[sub], CAP_SUB);

    for (int i = tid; i < 56; i += 256) { sdeg[i] = 0; scur[i] = 0; sden[i] = 0.f; }
    __syncthreads();

    for (int i = tid; i < cnt; i += 256) {
        int p = part2[s0 + i];
        sstage[i] = p;
        int local = p >> 17;
        if (local >= lo && local < hi) atomicAdd(&sdeg[local - lo], 1);
    }
    __syncthreads();

    if (tid < 64) {
        int v = (tid < nloc) ? sdeg[tid] : 0;
        int sc = v;
        #pragma unroll
        for (int o = 1; o < 64; o <<= 1) {
            int t2 = __shfl_up(sc, o, 64);
            if (tid >= o) sc += t2;
        }
        soff[tid + 1] = sc;
        if (tid == 0) soff[0] = 0;
    }
    __syncthreads();

    const bool fits = (soff[nloc] <= CAP2);

    if (fits) {
        for (int i = tid; i < cnt; i += 256) {
            int p = sstage[i];
            int local = p >> 17;
            if (local >= lo && local < hi) {
                int l2 = local - lo;
                int s = p & 0x1FFFF;
                int pos = soff[l2] + atomicAdd(&scur[l2], 1);
                float e = a_src[s] + a_dst[nb0 + local];
                e = (e >= 0.f) ? e : NEG_SLOPE * e;
                float ex = __expf(e);
                sedge[pos] = make_int2(s << 3, __float_as_int(ex));
                atomicAdd(&sden[l2], ex);
            }
        }
    }
    __syncthreads();

    if (fits) {
        const int group = tid >> 3;
        const int l8    = tid & 7;
        for (int n = group; n < nloc; n += 32) {
            int beg = soff[n], deg = sdeg[n];
            f32x4 a0 = {0.f,0.f,0.f,0.f}, a1 = {0.f,0.f,0.f,0.f};
            for (int i = 0; i < deg; ++i) {
                int2 me = sedge[beg + i];
                float w = __int_as_float(me.y);
                u16x8 zr = zb8[(size_t)me.x + l8];
                a0[0] = fmaf(w, bf2f(zr[0]), a0[0]);
                a0[1] = fmaf(w, bf2f(zr[1]), a0[1]);
                a0[2] = fmaf(w, bf2f(zr[2]), a0[2]);
                a0[3] = fmaf(w, bf2f(zr[3]), a0[3]);
                a1[0] = fmaf(w, bf2f(zr[4]), a1[0]);
                a1[1] = fmaf(w, bf2f(zr[5]), a1[1]);
                a1[2] = fmaf(w, bf2f(zr[6]), a1[2]);
                a1[3] = fmaf(w, bf2f(zr[7]), a1[3]);
            }
            float inv = (deg > 0) ? 1.f / sden[n] : 0.f;
            float* op = out + (size_t)(nb0 + lo + n) * D + 2 * l8;
            *(float2*)(op)      = make_float2(a0[0] * inv, a1[0] * inv);
            *(float2*)(op + 16) = make_float2(a0[1] * inv, a1[1] * inv);
            *(float2*)(op + 32) = make_float2(a0[2] * inv, a1[2] * inv);
            *(float2*)(op + 48) = make_float2(a0[3] * inv, a1[3] * inv);
        }
    } else {
        const ushort4* zb4 = (const ushort4*)zb8;
        const int wave = tid >> 6, lane = tid & 63, l16 = lane & 15;
        for (int n = wave; n < nloc; n += 4) {
            int deg = 0;
            float adn = a_dst[nb0 + lo + n];
            float dsum = 0.f;
            float4 acc = make_float4(0.f, 0.f, 0.f, 0.f);
            for (int c = 0; c < cnt; c += 64) {
                int j = c + lane;
                float ex = 0.f;
                if (j < cnt) {
                    int p = sstage[j];
                    if ((p >> 17) == lo + n) {
                        float e = a_src[p & 0x1FFFF] + adn;
                        e = (e >= 0.f) ? e : NEG_SLOPE * e;
                        ex = __expf(e);
                        ++deg;
                    }
                }
                float exs = ex;
                #pragma unroll
                for (int o = 32; o > 0; o >>= 1) exs += __shfl_xor(exs, o, 64);
                dsum += exs;
            }
            #pragma unroll
            for (int o = 32; o > 0; o >>= 1) deg += __shfl_xor(deg, o, 64);
            for (int j = 0; j < cnt; ++j) {
                int p = sstage[j];
                if ((p >> 17) == lo + n) {
                    int s = p & 0x1FFFF;
                    float e = a_src[s] + adn;
                    e = (e >= 0.f) ? e : NEG_SLOPE * e;
                    float w = __expf(e);
                    if (lane < 16) {
                        ushort4 zr = zb4[(size_t)(s << 4) + l16];   // positions l16*4+t
                        acc.x = fmaf(w, bf2f(zr.x), acc.x);
                        acc.y = fmaf(w, bf2f(zr.y), acc.y);
                        acc.z = fmaf(w, bf2f(zr.z), acc.z);
                        acc.w = fmaf(w, bf2f(zr.w), acc.w);
                    }
                }
            }
            #pragma unroll
            for (int o = 16; o <= 32; o <<= 1) {
                acc.x += __shfl_xor(acc.x, o, 64);
                acc.y += __shfl_xor(acc.y, o, 64);
                acc.z += __shfl_xor(acc.z, o, 64);
                acc.w += __shfl_xor(acc.w, o, 64);
            }
            if (lane < 16) {
                float inv = (deg > 0) ? 1.f / dsum : 0.f;
                float* op = out + (size_t)(nb0 + lo + n) * D + l16;
                op[0]  = acc.x * inv;   // col 0*16+l16
                op[16] = acc.y * inv;   // col 1*16+l16
                op[32] = acc.z * inv;
                op[48] = acc.w * inv;
            }
        }
    }
}

extern "C" void kernel_launch(void* const* d_in, const int* in_sizes, int n_in,
                              void* d_out, int out_size, void* d_ws, size_t ws_size,
                              hipStream_t stream) {
    const float* h      = (const float*)d_in[0];
    const int*   src    = (const int*)d_in[1];
    const int*   dst    = (const int*)d_in[2];
    const float* fc_w   = (const float*)d_in[3];
    const float* attn_w = (const float*)d_in[4];

    const int n_nodes = in_sizes[0] / IN;
    const int n_edges = in_sizes[1];
    float* out = (float*)d_out;

    const int nps2 = (n_nodes + NSUB - 1) / NSUB;   // nodes per sub-bucket (98)
    const int nps1 = nps2 * SUBPS;                  // nodes per slice (3136)
    const int nba  = (n_edges + EPB_A - 1) / EPB_A; // partA blocks (481)
    const int n_proj = (n_nodes + 255) / 256;       // projection blocks (391)
    const unsigned M1 = (unsigned)((0x100000000ULL + nps1 - 1) / (unsigned)nps1);
    const unsigned M2 = (unsigned)((0x100000000ULL + nps2 - 1) / (unsigned)nps2);

    // workspace layout
    char* p = (char*)d_ws;
    unsigned short* zb = (unsigned short*)p; p += (size_t)n_nodes * D * sizeof(unsigned short);
    int*   partA     = (int*)p;   p += (size_t)NSLICE * CAP_S * sizeof(int);
    int*   part2     = (int*)p;   p += (size_t)NSUB * CAP_SUB * sizeof(int);
    float* a_src     = (float*)p; p += (size_t)n_nodes * sizeof(float);
    float* a_dst     = (float*)p; p += (size_t)n_nodes * sizeof(float);
    int*   slice_cur = (int*)p;   p += NSLICE * 16 * sizeof(int);
    int*   sub_cur   = (int*)p;   p += NSUB * sizeof(int);

    // zero both cursor arrays (contiguous) each call
    hipMemsetAsync(slice_cur, 0, (NSLICE * 16 + NSUB) * sizeof(int), stream);

    k_partA_proj<<<dim3(nba + n_proj), dim3(256), 0, stream>>>(
        src, dst, slice_cur, partA, n_edges, nps1, M1, nba,
        h, fc_w, attn_w, zb, a_src, a_dst, n_nodes);
    k_partB<<<dim3(NSLICE * 32), dim3(256), 0, stream>>>(
        partA, slice_cur, sub_cur, part2, nps2, M2);
    k_fused<<<dim3(NSUB * 2), dim3(256), 0, stream>>>(
        part2, sub_cur, a_src, a_dst, (const u16x8*)zb, out, n_nodes, nps2);
}